// Round 8
// baseline (230.829 us; speedup 1.0000x reference)
//
#include <hip/hip_runtime.h>
#include <stdint.h>

#define DEVINL __device__ __forceinline__

typedef __attribute__((ext_vector_type(8))) __bf16 bf16x8;
typedef __attribute__((ext_vector_type(4))) float f32x4;
typedef __attribute__((ext_vector_type(16))) float f32x16;
typedef __attribute__((ext_vector_type(4))) int i32x4;
typedef __attribute__((ext_vector_type(8))) int i32x8;

// ---------- helpers ----------
DEVINL unsigned short f2bf(float f) {
  union { float f; unsigned int u; } v; v.f = f;
  unsigned int u = v.u;
  return (unsigned short)((u + 0x7fffu + ((u >> 16) & 1u)) >> 16);  // RNE
}

// float -> OCP e4m3 byte via HW cvt (gfx950 = OCP semantics)
DEVINL unsigned char f2fp8(float f) {
  return (unsigned char)(__builtin_amdgcn_cvt_pk_fp8_f32(f, f, 0, false) & 0xff);
}

DEVINL float sigm(float x) { return __builtin_amdgcn_rcpf(1.f + __expf(-x)); }
// tanh = 1 - 2/(1+e^{2x}); inf-safe both directions.
DEVINL float tanh_(float x) {
  return 1.f - 2.f * __builtin_amdgcn_rcpf(1.f + __expf(2.f * x));
}

// Operand-order ("tiled") global layout for gemm2's fp8 operands.
// 2048-B panel per (32-row block, 64-k block): [h=(k>>4)&1][g=(k>>5)&1][row&31][k&15]
// Lane l (r31=l&31, g2=l>>5) of a 32x32x64 MFMA needs k = g2*32+[0..31]:
// lo 16B at panel + g2*512 + r31*16, hi 16B at +1024. A wave's 64 lanes cover
// 1024 contiguous bytes per half -> coalesced, bytes land directly in MFMA
// operand order. For a fixed 32-row block, the 8 K-panels are CONTIGUOUS
// (16 KB) -> whole-K staging is 16 back-to-back 1KB gload_lds.
DEVINL size_t opt_off(int row, int k) {
  return (size_t)((row >> 5) * 8 + (k >> 6)) * 2048 + ((k >> 4) & 1) * 1024 +
         ((k >> 5) & 1) * 512 + (row & 31) * 16 + (k & 15);
}

// async global->LDS 16B per lane; lds base wave-uniform, HW scatters lane i to base+i*16
#define GLD_LDS16(gptr, lptr)                                                  \
  __builtin_amdgcn_global_load_lds(                                            \
      (__attribute__((address_space(1))) void*)(gptr),                         \
      (__attribute__((address_space(3))) void*)(lptr), 16, 0, 0)

// Stage-before-barrier pipeline (gemm1): STAGE(k+1) issued BEFORE the
// top barrier; TOPBAR_N waits vmcnt(N). Last iter peels to vmcnt(0).
#define TOPBAR_4 asm volatile("s_waitcnt vmcnt(4) lgkmcnt(0)\n\ts_barrier" ::: "memory")
#define TOPBAR_0 asm volatile("s_waitcnt vmcnt(0) lgkmcnt(0)\n\ts_barrier" ::: "memory")
#define BOTBAR   asm volatile("s_waitcnt lgkmcnt(0)\n\ts_barrier" ::: "memory")

// bf16-path XOR swizzle (gemm1, measured 0-conflict): staging chunk c takes
// source chunk (c&3)^((c>>3)&3); read koff = (q ^ ((fr>>1)&3)).
DEVINL int swz_col(int c) { return ((c & 3) ^ ((c >> 3) & 3)) * 8; }   // bf16: *8 shorts = 16B

// ---------- fused prep: concat + weight cvt + hvec + Q zero, grid-sectioned ----------
__global__ void prep_all(const float* __restrict__ obs, const float* __restrict__ act,
                         const float* __restrict__ W1, const float* __restrict__ Wih,
                         const float* __restrict__ W2, const float* __restrict__ Whh,
                         const float* __restrict__ hid, const float* __restrict__ bhh,
                         const float* __restrict__ bih,
                         unsigned short* __restrict__ A0, unsigned short* __restrict__ W1b,
                         unsigned char* __restrict__ Wih8, unsigned short* __restrict__ W2b,
                         float* __restrict__ hvec, float* __restrict__ Qz) {
  const int bid = blockIdx.x, tid = threadIdx.x;
  if (bid < 2176) {
    // section A: concat(obs, act) -> bf16 [32768, 544]
    const int total = 32768 * 68;
    for (int c = bid * 256 + tid; c < total; c += 2176 * 256) {
      const int b = c / 68, c8 = c % 68;
      const float* src = (c8 < 64) ? (obs + (size_t)b * 512 + c8 * 8)
                                   : (act + (size_t)b * 32 + (c8 - 64) * 8);
      float4 f0 = *(const float4*)src;
      float4 f1 = *(const float4*)(src + 4);
      unsigned short u[8] = {f2bf(f0.x), f2bf(f0.y), f2bf(f0.z), f2bf(f0.w),
                             f2bf(f1.x), f2bf(f1.y), f2bf(f1.z), f2bf(f1.w)};
      *(uint4*)(A0 + (size_t)b * 544 + c8 * 8) = *(uint4*)u;
    }
  } else if (bid < 2176 + 1312) {
    // section B: weight conversion (one float4 per thread)
    const int i = (bid - 2176) * 256 + tid;
    if (i < 69632) {                       // W1 -> bf16
      float4 f = *(const float4*)(W1 + (size_t)i * 4);
      unsigned short u[4] = {f2bf(f.x), f2bf(f.y), f2bf(f.z), f2bf(f.w)};
      *(uint2*)(W1b + (size_t)i * 4) = *(uint2*)u;
    } else if (i < 69632 + 262144) {       // Wih -> fp8 e4m3 x16, operand-tiled layout
      const int off = i - 69632;
      const int row = off >> 7, col0 = (off & 127) * 4;  // 4 consecutive cols, same 16B chunk
      float4 f = *(const float4*)(Wih + (size_t)off * 4);
      int pk = __builtin_amdgcn_cvt_pk_fp8_f32(f.x * 16.f, f.y * 16.f, 0, false);
      pk = __builtin_amdgcn_cvt_pk_fp8_f32(f.z * 16.f, f.w * 16.f, pk, true);
      *(unsigned int*)(Wih8 + opt_off(row, col0)) = (unsigned int)pk;
    } else {                               // W2 -> bf16
      const int off = i - 331776;
      float4 f = *(const float4*)(W2 + (size_t)off * 4);
      unsigned short u[4] = {f2bf(f.x), f2bf(f.y), f2bf(f.z), f2bf(f.w)};
      *(uint2*)(W2b + (size_t)off * 4) = *(uint2*)u;
    }
  } else if (bid < 4000) {
    // section C: hvec[j] = dot(W_hh[j,:], hid) + b_hh[j] + b_ih[j]
    const int j = (bid - 3488) * 4 + (tid >> 6);
    const int lane = tid & 63;
    const float* w = Whh + (size_t)j * 512;
    float s = 0.f;
    for (int k = lane; k < 512; k += 64) s += w[k] * hid[k];
    for (int off = 32; off; off >>= 1) s += __shfl_down(s, off, 64);
    if (lane == 0) hvec[j] = s + bhh[j] + bih[j];
  } else {
    // section D: zero Q (gemm2's fused-gemm3 atomics accumulate into it).
    // Runs EVERY launch -> safe under output re-poisoning between iterations.
    const int i = (bid - 4000) * 256 + tid;  // 512 blocks x 256 thr x 8 floats = 4 MB
    float4 z = {};
    *(float4*)(Qz + (size_t)i * 8) = z;
    *(float4*)(Qz + (size_t)i * 8 + 4) = z;
  }
}

// ---------- GEMM1: X8 = fp8(relu(A0 @ W1^T + b1) * 8), operand-tiled out ----------
__global__ __launch_bounds__(256, 2) void gemm1_relu(
    const unsigned short* __restrict__ A0,   // [32768,544] bf16
    const unsigned short* __restrict__ W1b,  // [512,544] bf16
    const float* __restrict__ b1,            // [512]
    unsigned char* __restrict__ X8) {        // [32768,512] fp8 (x8, operand-tiled)
  constexpr int KT = 17, LD = 544;
  __shared__ __align__(16) unsigned short As[2][128 * 32];  // 16 KB
  __shared__ __align__(16) unsigned short Bs[2][128 * 32];  // 16 KB
  const int tid = threadIdx.x, wave = tid >> 6, lane = tid & 63;
  const int id = blockIdx.x, xcd = id & 7, slot = id >> 3;  // 1024 blocks
  const int m0 = (xcd * 32 + (slot >> 2)) * 128;            // 256 m-tiles
  const int n0 = (slot & 3) * 128;                          // 4 n-tiles
  const int wr = (wave >> 1) * 64, wc = (wave & 1) * 64;
  f32x4 acc[4][4] = {};

  const int c0 = tid, c1 = tid + 256;
  const unsigned short* pA0 = A0 + (size_t)(m0 + (c0 >> 2)) * LD + swz_col(c0);
  const unsigned short* pA1 = A0 + (size_t)(m0 + (c1 >> 2)) * LD + swz_col(c1);
  const unsigned short* pB0 = W1b + (size_t)(n0 + (c0 >> 2)) * LD + swz_col(c0);
  const unsigned short* pB1 = W1b + (size_t)(n0 + (c1 >> 2)) * LD + swz_col(c1);
  const int fr = lane & 15, q = lane >> 4;
  const int koff = (q ^ ((fr >> 1) & 3)) * 8;

#define STAGE1(buf)                                                            \
  do {                                                                         \
    GLD_LDS16(pA0, &As[(buf)][wave * 512]);                                    \
    GLD_LDS16(pA1, &As[(buf)][2048 + wave * 512]);                             \
    GLD_LDS16(pB0, &Bs[(buf)][wave * 512]);                                    \
    GLD_LDS16(pB1, &Bs[(buf)][2048 + wave * 512]);                             \
    pA0 += 32; pA1 += 32; pB0 += 32; pB1 += 32;                                \
  } while (0)

  STAGE1(0);
  for (int kt = 0; kt < KT; ++kt) {
    if (kt + 1 < KT) { STAGE1((kt + 1) & 1); TOPBAR_4; } else { TOPBAR_0; }
    const unsigned short* as = As[kt & 1];
    const unsigned short* bs = Bs[kt & 1];
    bf16x8 a[4], b[4];
#pragma unroll
    for (int i = 0; i < 4; ++i) a[i] = *(const bf16x8*)&as[(wr + i * 16 + fr) * 32 + koff];
#pragma unroll
    for (int j = 0; j < 4; ++j) b[j] = *(const bf16x8*)&bs[(wc + j * 16 + fr) * 32 + koff];
#pragma unroll
    for (int i = 0; i < 4; ++i)
#pragma unroll
      for (int j = 0; j < 4; ++j)
        acc[i][j] = __builtin_amdgcn_mfma_f32_16x16x32_bf16(a[i], b[j], acc[i][j], 0, 0, 0);
    BOTBAR;
  }
#undef STAGE1
  const int rbase = q * 4, cn = fr;
#pragma unroll
  for (int i = 0; i < 4; ++i)
#pragma unroll
    for (int j = 0; j < 4; ++j) {
      const int gn = n0 + wc + j * 16 + cn;
      const float bias = b1[gn];
#pragma unroll
      for (int r = 0; r < 4; ++r) {
        const int gm = m0 + wr + i * 16 + rbase + r;
        float v = acc[i][j][r] + bias;
        v = v > 0.f ? v : 0.f;
        X8[opt_off(gm, gn)] = f2fp8(v * 8.f);
      }
    }
}

// ---------- GEMM2 MX-fp8 32x32x64 + LSTM + FUSED gemm3 (Q via atomics) --------
// Main loop identical to R7 (B-in-LDS-once, A triple-buffered direct loads).
// Epilogue: instead of writing H (33.5 MB) for a separate gemm3 to re-read,
// compute the block's PARTIAL Q = hnew_tile[64x32] @ W2T[32x32] per wave with
// 4x mfma_f32_32x32x16_bf16 and atomicAdd f32 into Q (16 partials/output,
// lanes coalesced 128 B). hnew transpose (col-per-lane -> row-per-lane A-frag)
// via LDS reusing Bs (stride 68 B: writes 2-way/free, reads bank-spread).
// Q is zeroed by prep section D each launch; bias added by the n0==0 block.
__global__ __launch_bounds__(256, 2) void gemm2_lstm(
    const unsigned char* __restrict__ X8,    // [32768,512] fp8, operand-tiled
    const unsigned char* __restrict__ Wih8,  // [2048,512] fp8, operand-tiled
    const float* __restrict__ hvec,          // [2048]
    const float* __restrict__ cell,          // [512]
    const unsigned short* __restrict__ W2b,  // [32,512] bf16
    const float* __restrict__ b2,            // [32]
    float* __restrict__ Q,                   // [32768,32] fp32 out (atomic acc)
    float* __restrict__ hlast,               // [512] fp32 out
    float* __restrict__ clast) {             // [512] fp32 out
  __shared__ __align__(16) unsigned char Bs[4 * 16384];      // 64 KB: [quad][kt*2048+h*1024]
  const int tid = threadIdx.x, wave = tid >> 6, lane = tid & 63;
  const int id = blockIdx.x, xcd = id & 7, slot = id >> 3;  // 2048 blocks
  const int m0 = (xcd * 16 + (slot >> 4)) * 256;            // 128 m-tiles
  const int n0 = (slot & 15) * 32;                          // 16 quadrant-col tiles
  const int r31 = lane & 31, g2 = lane >> 5;
  const int voff = g2 * 512 + r31 * 16;  // lane's operand offset within a panel

  // ---- prologue: stage ALL of B (this block's 4 quads x 8 kt) into LDS ----
  {
    const unsigned char* bsrc =
        Wih8 + (size_t)(wave * 16 + (n0 >> 5)) * 16384 + lane * 16;
#pragma unroll
    for (int s = 0; s < 16; ++s)
      GLD_LDS16(bsrc + s * 1024, &Bs[wave * 16384 + s * 1024]);
  }

  // ---- A prefetch (triple-buffered, depth 2) ----
  const unsigned char* pa = X8 + (size_t)((m0 >> 5) + wave * 2) * 16384 + voff;
  i32x8 Aa[3], Ab[3];
#define LDA(buf, kt)                                                           \
  do {                                                                         \
    i32x4 lo0 = *(const i32x4*)(pa + (kt) * 2048);                             \
    i32x4 hi0 = *(const i32x4*)(pa + (kt) * 2048 + 1024);                      \
    Aa[buf] = __builtin_shufflevector(lo0, hi0, 0, 1, 2, 3, 4, 5, 6, 7);       \
    i32x4 lo1 = *(const i32x4*)(pa + 16384 + (kt) * 2048);                     \
    i32x4 hi1 = *(const i32x4*)(pa + 16384 + (kt) * 2048 + 1024);              \
    Ab[buf] = __builtin_shufflevector(lo1, hi1, 0, 1, 2, 3, 4, 5, 6, 7);       \
  } while (0)

#define MFMA_MX(acc_, a_, b_)                                                  \
  acc_ = __builtin_amdgcn_mfma_scale_f32_32x32x64_f8f6f4(                      \
      a_, b_, acc_, 0, 0, 0, 0x7f7f7f7f, 0, 0x7f7f7f7f)

  LDA(0, 0);
  LDA(1, 1);
  __syncthreads();  // B visible; only block-wide barrier before epilogue

  // 8 accumulators: [frag f=0,1][gate quadrant 0..3]
  f32x16 acc00 = {}, acc01 = {}, acc02 = {}, acc03 = {};
  f32x16 acc10 = {}, acc11 = {}, acc12 = {}, acc13 = {};

#pragma unroll
  for (int kt = 0; kt < 8; ++kt) {
    const int cur = kt % 3, nx = (kt + 2) % 3;  // compile-time after unroll
    if (kt < 6) LDA(nx, kt + 2);                // issue-early: 2-kt lead on HBM
    i32x8 B0, B1, B2, B3;
    {
      const unsigned char* bb = &Bs[kt * 2048 + lane * 16];
      i32x4 l0 = *(const i32x4*)(bb);
      i32x4 h0 = *(const i32x4*)(bb + 1024);
      i32x4 l1 = *(const i32x4*)(bb + 16384);
      i32x4 h1 = *(const i32x4*)(bb + 16384 + 1024);
      i32x4 l2 = *(const i32x4*)(bb + 32768);
      i32x4 h2 = *(const i32x4*)(bb + 32768 + 1024);
      i32x4 l3 = *(const i32x4*)(bb + 49152);
      i32x4 h3 = *(const i32x4*)(bb + 49152 + 1024);
      B0 = __builtin_shufflevector(l0, h0, 0, 1, 2, 3, 4, 5, 6, 7);
      B1 = __builtin_shufflevector(l1, h1, 0, 1, 2, 3, 4, 5, 6, 7);
      B2 = __builtin_shufflevector(l2, h2, 0, 1, 2, 3, 4, 5, 6, 7);
      B3 = __builtin_shufflevector(l3, h3, 0, 1, 2, 3, 4, 5, 6, 7);
    }
    MFMA_MX(acc00, Aa[cur], B0); MFMA_MX(acc01, Aa[cur], B1);
    MFMA_MX(acc02, Aa[cur], B2); MFMA_MX(acc03, Aa[cur], B3);
    MFMA_MX(acc10, Ab[cur], B0); MFMA_MX(acc11, Ab[cur], B1);
    MFMA_MX(acc12, Ab[cur], B2); MFMA_MX(acc13, Ab[cur], B3);
  }
#undef LDA
#undef MFMA_MX

  // ---- epilogue: LSTM gates -> hnew -> fused partial Q ----
  const int gn = n0 + r31;  // h-column in [0,512)
  const float hv_i = hvec[gn];
  const float hv_f = hvec[gn + 512];
  const float hv_g = hvec[gn + 1024];
  const float hv_o = hvec[gn + 1536];
  const float cprev = cell[gn];
  constexpr float S = 1.f / 128.f;  // undo x8 (X) * x16 (Wih)

  __syncthreads();  // all waves done reading Bs -> safe to reuse as transpose buf
  unsigned char* tb = &Bs[wave * 4352];  // 64 rows x 68 B (bank-spread stride)

#define EPILOG(F, ai, af, ag, ao)                                              \
  _Pragma("unroll")                                                            \
  for (int rg = 0; rg < 4; ++rg) {                                             \
    _Pragma("unroll")                                                          \
    for (int rr = 0; rr < 4; ++rr) {                                           \
      const int reg = rg * 4 + rr;                                             \
      const int row64 = (F) * 32 + rr + rg * 8 + g2 * 4;                       \
      float si = sigm(ai[reg] * S + hv_i);                                     \
      float sf = sigm(af[reg] * S + hv_f);                                     \
      float tg = tanh_(ag[reg] * S + hv_g);                                    \
      float so = sigm(ao[reg] * S + hv_o);                                     \
      float cnew = sf * cprev + si * tg;                                       \
      float hnew = so * tanh_(cnew);                                           \
      *(unsigned short*)(tb + row64 * 68 + r31 * 2) = f2bf(hnew);              \
      if (m0 + wave * 64 + row64 == 32767) { hlast[gn] = hnew; clast[gn] = cnew; } \
    }                                                                          \
  }

  EPILOG(0, acc00, acc01, acc02, acc03)
  EPILOG(1, acc10, acc11, acc12, acc13)
#undef EPILOG

  // W2 B-frags (mfma_f32_32x32x16_bf16: lane -> col n=l&31(=q), k=(l>>5)*8+j)
  const bf16x8 w0 = *(const bf16x8*)&W2b[(size_t)r31 * 512 + n0 + g2 * 8];       // k 0..15
  const bf16x8 w1 = *(const bf16x8*)&W2b[(size_t)r31 * 512 + n0 + 16 + g2 * 8];  // k 16..31

  // hnew A-frags from LDS (lane -> row l&31, k=(l>>5)*8+j); stride 68 -> b32 reads
  f32x16 qp0 = {}, qp1 = {};
#pragma unroll
  for (int F = 0; F < 2; ++F) {
    bf16x8 a0, a1;
    __builtin_memcpy(&a0, tb + (F * 32 + r31) * 68 + g2 * 16, 16);       // k 0..15
    __builtin_memcpy(&a1, tb + (F * 32 + r31) * 68 + g2 * 16 + 32, 16);  // k 16..31
    if (F == 0) {
      qp0 = __builtin_amdgcn_mfma_f32_32x32x16_bf16(a0, w0, qp0, 0, 0, 0);
      qp0 = __builtin_amdgcn_mfma_f32_32x32x16_bf16(a1, w1, qp0, 0, 0, 0);
    } else {
      qp1 = __builtin_amdgcn_mfma_f32_32x32x16_bf16(a0, w0, qp1, 0, 0, 0);
      qp1 = __builtin_amdgcn_mfma_f32_32x32x16_bf16(a1, w1, qp1, 0, 0, 0);
    }
  }

  // bias once per (gm,q): only the n0==0 block adds it
  const float bv = (n0 == 0) ? b2[r31] : 0.f;
  // C/D: col(q)=lane&31, row=(reg&3)+8*(reg>>2)+4*(lane>>5)
#pragma unroll
  for (int reg = 0; reg < 16; ++reg) {
    const int row = (reg & 3) + 8 * (reg >> 2) + 4 * g2;
    atomicAdd(&Q[(size_t)(m0 + wave * 64 + row) * 32 + r31], qp0[reg] + bv);
    atomicAdd(&Q[(size_t)(m0 + wave * 64 + 32 + row) * 32 + r31], qp1[reg] + bv);
  }
}

// ---------- launch ----------
extern "C" void kernel_launch(void* const* d_in, const int* in_sizes, int n_in,
                              void* d_out, int out_size, void* d_ws, size_t ws_size,
                              hipStream_t stream) {
  const float* obs  = (const float*)d_in[0];
  const float* act  = (const float*)d_in[1];
  const float* hid  = (const float*)d_in[2];
  const float* cell = (const float*)d_in[3];
  const float* W1   = (const float*)d_in[4];
  const float* b1   = (const float*)d_in[5];
  const float* Wih  = (const float*)d_in[6];
  const float* bih  = (const float*)d_in[7];
  const float* Whh  = (const float*)d_in[8];
  const float* bhh  = (const float*)d_in[9];
  const float* W2   = (const float*)d_in[10];
  const float* b2   = (const float*)d_in[11];
  float* out = (float*)d_out;

  char* ws = (char*)d_ws;
  unsigned short* A0   = (unsigned short*)(ws);              // [B,544] bf16 (35,651,584 B)
  unsigned char*  X8   = (unsigned char*)(ws + 35651584);    // [B,512] fp8 tiled (16,777,216 B)
  unsigned short* W1b  = (unsigned short*)(ws + 52428800);   // 557,056 B
  unsigned char*  Wih8 = (unsigned char*)(ws + 52985856);    // 1,048,576 B
  unsigned short* W2b  = (unsigned short*)(ws + 54034432);   // 32,768 B
  float*          hvec = (float*)(ws + 54067200);            // 8,192 B

  prep_all<<<4512, 256, 0, stream>>>(obs, act, W1, Wih, W2, Whh, hid, bhh, bih,
                                     A0, W1b, Wih8, W2b, hvec, out);
  gemm1_relu<<<1024, 256, 0, stream>>>(A0, W1b, b1, X8);
  gemm2_lstm<<<2048, 256, 0, stream>>>(X8, Wih8, hvec, cell, W2b, b2, out,
                                       out + 32768 * 32,
                                       out + 32768 * 32 + 512);
}

// Round 9
// 208.100 us; speedup vs baseline: 1.1092x; 1.1092x over previous
//
#include <hip/hip_runtime.h>
#include <stdint.h>

#define DEVINL __device__ __forceinline__

typedef __attribute__((ext_vector_type(8))) __bf16 bf16x8;
typedef __attribute__((ext_vector_type(4))) float f32x4;
typedef __attribute__((ext_vector_type(16))) float f32x16;
typedef __attribute__((ext_vector_type(4))) int i32x4;
typedef __attribute__((ext_vector_type(8))) int i32x8;

// ---------- helpers ----------
DEVINL unsigned short f2bf(float f) {
  union { float f; unsigned int u; } v; v.f = f;
  unsigned int u = v.u;
  return (unsigned short)((u + 0x7fffu + ((u >> 16) & 1u)) >> 16);  // RNE
}

// float -> OCP e4m3 byte via HW cvt (gfx950 = OCP semantics)
DEVINL unsigned char f2fp8(float f) {
  return (unsigned char)(__builtin_amdgcn_cvt_pk_fp8_f32(f, f, 0, false) & 0xff);
}

DEVINL float sigm(float x) { return __builtin_amdgcn_rcpf(1.f + __expf(-x)); }
// tanh = 1 - 2/(1+e^{2x}); inf-safe both directions.
DEVINL float tanh_(float x) {
  return 1.f - 2.f * __builtin_amdgcn_rcpf(1.f + __expf(2.f * x));
}

// Operand-order ("tiled") global layout for gemm2's fp8 operands.
// 2048-B panel per (32-row block, 64-k block): [h=(k>>4)&1][g=(k>>5)&1][row&31][k&15]
// Lane l (r31=l&31, g2=l>>5) of a 32x32x64 MFMA needs k = g2*32+[0..31]:
// lo 16B at panel + g2*512 + r31*16, hi 16B at +1024. A wave's 64 lanes cover
// 1024 contiguous bytes per half -> coalesced, bytes land directly in MFMA
// operand order. For a fixed 32-row block, the 8 K-panels are CONTIGUOUS
// (16 KB) -> whole-K staging is 16 back-to-back 1KB gload_lds.
DEVINL size_t opt_off(int row, int k) {
  return (size_t)((row >> 5) * 8 + (k >> 6)) * 2048 + ((k >> 4) & 1) * 1024 +
         ((k >> 5) & 1) * 512 + (row & 31) * 16 + (k & 15);
}

// async global->LDS 16B per lane; lds base wave-uniform, HW scatters lane i to base+i*16
#define GLD_LDS16(gptr, lptr)                                                  \
  __builtin_amdgcn_global_load_lds(                                            \
      (__attribute__((address_space(1))) void*)(gptr),                         \
      (__attribute__((address_space(3))) void*)(lptr), 16, 0, 0)

// Stage-before-barrier pipeline (gemm1): STAGE(k+1) issued BEFORE the
// top barrier; TOPBAR_N waits vmcnt(N). Last iter peels to vmcnt(0).
#define TOPBAR_4 asm volatile("s_waitcnt vmcnt(4) lgkmcnt(0)\n\ts_barrier" ::: "memory")
#define TOPBAR_0 asm volatile("s_waitcnt vmcnt(0) lgkmcnt(0)\n\ts_barrier" ::: "memory")
#define BOTBAR   asm volatile("s_waitcnt lgkmcnt(0)\n\ts_barrier" ::: "memory")

// bf16-path XOR swizzle (gemm1, measured 0-conflict): staging chunk c takes
// source chunk (c&3)^((c>>3)&3); read koff = (q ^ ((fr>>1)&3)).
DEVINL int swz_col(int c) { return ((c & 3) ^ ((c >> 3) & 3)) * 8; }   // bf16: *8 shorts = 16B

// ---------- fused prep: input concat + weight cvt + hvec, grid-sectioned ----------
__global__ void prep_all(const float* __restrict__ obs, const float* __restrict__ act,
                         const float* __restrict__ W1, const float* __restrict__ Wih,
                         const float* __restrict__ W2, const float* __restrict__ Whh,
                         const float* __restrict__ hid, const float* __restrict__ bhh,
                         const float* __restrict__ bih,
                         unsigned short* __restrict__ A0, unsigned short* __restrict__ W1b,
                         unsigned char* __restrict__ Wih8, unsigned short* __restrict__ W2b,
                         float* __restrict__ hvec) {
  const int bid = blockIdx.x, tid = threadIdx.x;
  if (bid < 2176) {
    // section A: concat(obs, act) -> bf16 [32768, 544]
    const int total = 32768 * 68;
    for (int c = bid * 256 + tid; c < total; c += 2176 * 256) {
      const int b = c / 68, c8 = c % 68;
      const float* src = (c8 < 64) ? (obs + (size_t)b * 512 + c8 * 8)
                                   : (act + (size_t)b * 32 + (c8 - 64) * 8);
      float4 f0 = *(const float4*)src;
      float4 f1 = *(const float4*)(src + 4);
      unsigned short u[8] = {f2bf(f0.x), f2bf(f0.y), f2bf(f0.z), f2bf(f0.w),
                             f2bf(f1.x), f2bf(f1.y), f2bf(f1.z), f2bf(f1.w)};
      *(uint4*)(A0 + (size_t)b * 544 + c8 * 8) = *(uint4*)u;
    }
  } else if (bid < 2176 + 1312) {
    // section B: weight conversion (one float4 per thread)
    const int i = (bid - 2176) * 256 + tid;
    if (i < 69632) {                       // W1 -> bf16
      float4 f = *(const float4*)(W1 + (size_t)i * 4);
      unsigned short u[4] = {f2bf(f.x), f2bf(f.y), f2bf(f.z), f2bf(f.w)};
      *(uint2*)(W1b + (size_t)i * 4) = *(uint2*)u;
    } else if (i < 69632 + 262144) {       // Wih -> fp8 e4m3 x16, operand-tiled layout
      const int off = i - 69632;
      const int row = off >> 7, col0 = (off & 127) * 4;  // 4 consecutive cols, same 16B chunk
      float4 f = *(const float4*)(Wih + (size_t)off * 4);
      int pk = __builtin_amdgcn_cvt_pk_fp8_f32(f.x * 16.f, f.y * 16.f, 0, false);
      pk = __builtin_amdgcn_cvt_pk_fp8_f32(f.z * 16.f, f.w * 16.f, pk, true);
      *(unsigned int*)(Wih8 + opt_off(row, col0)) = (unsigned int)pk;
    } else {                               // W2 -> bf16
      const int off = i - 331776;
      float4 f = *(const float4*)(W2 + (size_t)off * 4);
      unsigned short u[4] = {f2bf(f.x), f2bf(f.y), f2bf(f.z), f2bf(f.w)};
      *(uint2*)(W2b + (size_t)off * 4) = *(uint2*)u;
    }
  } else {
    // section C: hvec[j] = dot(W_hh[j,:], hid) + b_hh[j] + b_ih[j]
    const int j = (bid - 3488) * 4 + (tid >> 6);
    const int lane = tid & 63;
    const float* w = Whh + (size_t)j * 512;
    float s = 0.f;
    for (int k = lane; k < 512; k += 64) s += w[k] * hid[k];
    for (int off = 32; off; off >>= 1) s += __shfl_down(s, off, 64);
    if (lane == 0) hvec[j] = s + bhh[j] + bih[j];
  }
}

// ---------- GEMM1: X8 = fp8(relu(A0 @ W1^T + b1) * 8), operand-tiled out ----------
__global__ __launch_bounds__(256, 2) void gemm1_relu(
    const unsigned short* __restrict__ A0,   // [32768,544] bf16
    const unsigned short* __restrict__ W1b,  // [512,544] bf16
    const float* __restrict__ b1,            // [512]
    unsigned char* __restrict__ X8) {        // [32768,512] fp8 (x8, operand-tiled)
  constexpr int KT = 17, LD = 544;
  __shared__ __align__(16) unsigned short As[2][128 * 32];  // 16 KB
  __shared__ __align__(16) unsigned short Bs[2][128 * 32];  // 16 KB
  const int tid = threadIdx.x, wave = tid >> 6, lane = tid & 63;
  const int id = blockIdx.x, xcd = id & 7, slot = id >> 3;  // 1024 blocks
  const int m0 = (xcd * 32 + (slot >> 2)) * 128;            // 256 m-tiles
  const int n0 = (slot & 3) * 128;                          // 4 n-tiles
  const int wr = (wave >> 1) * 64, wc = (wave & 1) * 64;
  f32x4 acc[4][4] = {};

  const int c0 = tid, c1 = tid + 256;
  const unsigned short* pA0 = A0 + (size_t)(m0 + (c0 >> 2)) * LD + swz_col(c0);
  const unsigned short* pA1 = A0 + (size_t)(m0 + (c1 >> 2)) * LD + swz_col(c1);
  const unsigned short* pB0 = W1b + (size_t)(n0 + (c0 >> 2)) * LD + swz_col(c0);
  const unsigned short* pB1 = W1b + (size_t)(n0 + (c1 >> 2)) * LD + swz_col(c1);
  const int fr = lane & 15, q = lane >> 4;
  const int koff = (q ^ ((fr >> 1) & 3)) * 8;

#define STAGE1(buf)                                                            \
  do {                                                                         \
    GLD_LDS16(pA0, &As[(buf)][wave * 512]);                                    \
    GLD_LDS16(pA1, &As[(buf)][2048 + wave * 512]);                             \
    GLD_LDS16(pB0, &Bs[(buf)][wave * 512]);                                    \
    GLD_LDS16(pB1, &Bs[(buf)][2048 + wave * 512]);                             \
    pA0 += 32; pA1 += 32; pB0 += 32; pB1 += 32;                                \
  } while (0)

  STAGE1(0);
  for (int kt = 0; kt < KT; ++kt) {
    if (kt + 1 < KT) { STAGE1((kt + 1) & 1); TOPBAR_4; } else { TOPBAR_0; }
    const unsigned short* as = As[kt & 1];
    const unsigned short* bs = Bs[kt & 1];
    bf16x8 a[4], b[4];
#pragma unroll
    for (int i = 0; i < 4; ++i) a[i] = *(const bf16x8*)&as[(wr + i * 16 + fr) * 32 + koff];
#pragma unroll
    for (int j = 0; j < 4; ++j) b[j] = *(const bf16x8*)&bs[(wc + j * 16 + fr) * 32 + koff];
#pragma unroll
    for (int i = 0; i < 4; ++i)
#pragma unroll
      for (int j = 0; j < 4; ++j)
        acc[i][j] = __builtin_amdgcn_mfma_f32_16x16x32_bf16(a[i], b[j], acc[i][j], 0, 0, 0);
    BOTBAR;
  }
#undef STAGE1
  const int rbase = q * 4, cn = fr;
#pragma unroll
  for (int i = 0; i < 4; ++i)
#pragma unroll
    for (int j = 0; j < 4; ++j) {
      const int gn = n0 + wc + j * 16 + cn;
      const float bias = b1[gn];
#pragma unroll
      for (int r = 0; r < 4; ++r) {
        const int gm = m0 + wr + i * 16 + rbase + r;
        float v = acc[i][j][r] + bias;
        v = v > 0.f ? v : 0.f;
        X8[opt_off(gm, gn)] = f2fp8(v * 8.f);
      }
    }
}

// ---------- GEMM2 MX-fp8 32x32x64: B-in-LDS-once + deep-prefetch A + LSTM ------
// (R7 structure verbatim -- 47.5 us known-good. R8's fused-atomic epilogue
// regressed: device-scope atomics bypass the per-XCD L2 -> WRITE 65.5 MB.)
__global__ __launch_bounds__(256, 2) void gemm2_lstm(
    const unsigned char* __restrict__ X8,    // [32768,512] fp8, operand-tiled
    const unsigned char* __restrict__ Wih8,  // [2048,512] fp8, operand-tiled
    const float* __restrict__ hvec,          // [2048]
    const float* __restrict__ cell,          // [512]
    unsigned short* __restrict__ H,          // [32768,512] bf16 out
    float* __restrict__ hlast,               // [512] fp32 out
    float* __restrict__ clast) {             // [512] fp32 out
  __shared__ __align__(16) unsigned char Bs[4 * 16384];      // 64 KB: [quad][kt*2048+h*1024]
  const int tid = threadIdx.x, wave = tid >> 6, lane = tid & 63;
  const int id = blockIdx.x, xcd = id & 7, slot = id >> 3;  // 2048 blocks
  const int m0 = (xcd * 16 + (slot >> 4)) * 256;            // 128 m-tiles
  const int n0 = (slot & 15) * 32;                          // 16 quadrant-col tiles
  const int r31 = lane & 31, g2 = lane >> 5;
  const int voff = g2 * 512 + r31 * 16;  // lane's operand offset within a panel

  // ---- prologue: stage ALL of B (this block's 4 quads x 8 kt) into LDS ----
  {
    const unsigned char* bsrc =
        Wih8 + (size_t)(wave * 16 + (n0 >> 5)) * 16384 + lane * 16;
#pragma unroll
    for (int s = 0; s < 16; ++s)
      GLD_LDS16(bsrc + s * 1024, &Bs[wave * 16384 + s * 1024]);
  }

  // ---- A prefetch (triple-buffered, depth 2) ----
  const unsigned char* pa = X8 + (size_t)((m0 >> 5) + wave * 2) * 16384 + voff;
  i32x8 Aa[3], Ab[3];
#define LDA(buf, kt)                                                           \
  do {                                                                         \
    i32x4 lo0 = *(const i32x4*)(pa + (kt) * 2048);                             \
    i32x4 hi0 = *(const i32x4*)(pa + (kt) * 2048 + 1024);                      \
    Aa[buf] = __builtin_shufflevector(lo0, hi0, 0, 1, 2, 3, 4, 5, 6, 7);       \
    i32x4 lo1 = *(const i32x4*)(pa + 16384 + (kt) * 2048);                     \
    i32x4 hi1 = *(const i32x4*)(pa + 16384 + (kt) * 2048 + 1024);              \
    Ab[buf] = __builtin_shufflevector(lo1, hi1, 0, 1, 2, 3, 4, 5, 6, 7);       \
  } while (0)

#define MFMA_MX(acc_, a_, b_)                                                  \
  acc_ = __builtin_amdgcn_mfma_scale_f32_32x32x64_f8f6f4(                      \
      a_, b_, acc_, 0, 0, 0, 0x7f7f7f7f, 0, 0x7f7f7f7f)

  LDA(0, 0);
  LDA(1, 1);
  __syncthreads();  // B visible; only barrier in kernel

  // 8 accumulators: [frag f=0,1][gate quadrant 0..3]
  f32x16 acc00 = {}, acc01 = {}, acc02 = {}, acc03 = {};
  f32x16 acc10 = {}, acc11 = {}, acc12 = {}, acc13 = {};

#pragma unroll
  for (int kt = 0; kt < 8; ++kt) {
    const int cur = kt % 3, nx = (kt + 2) % 3;  // compile-time after unroll
    if (kt < 6) LDA(nx, kt + 2);                // issue-early: 2-kt lead on HBM
    i32x8 B0, B1, B2, B3;
    {
      const unsigned char* bb = &Bs[kt * 2048 + lane * 16];
      i32x4 l0 = *(const i32x4*)(bb);
      i32x4 h0 = *(const i32x4*)(bb + 1024);
      i32x4 l1 = *(const i32x4*)(bb + 16384);
      i32x4 h1 = *(const i32x4*)(bb + 16384 + 1024);
      i32x4 l2 = *(const i32x4*)(bb + 32768);
      i32x4 h2 = *(const i32x4*)(bb + 32768 + 1024);
      i32x4 l3 = *(const i32x4*)(bb + 49152);
      i32x4 h3 = *(const i32x4*)(bb + 49152 + 1024);
      B0 = __builtin_shufflevector(l0, h0, 0, 1, 2, 3, 4, 5, 6, 7);
      B1 = __builtin_shufflevector(l1, h1, 0, 1, 2, 3, 4, 5, 6, 7);
      B2 = __builtin_shufflevector(l2, h2, 0, 1, 2, 3, 4, 5, 6, 7);
      B3 = __builtin_shufflevector(l3, h3, 0, 1, 2, 3, 4, 5, 6, 7);
    }
    MFMA_MX(acc00, Aa[cur], B0); MFMA_MX(acc01, Aa[cur], B1);
    MFMA_MX(acc02, Aa[cur], B2); MFMA_MX(acc03, Aa[cur], B3);
    MFMA_MX(acc10, Ab[cur], B0); MFMA_MX(acc11, Ab[cur], B1);
    MFMA_MX(acc12, Ab[cur], B2); MFMA_MX(acc13, Ab[cur], B3);
  }
#undef LDA
#undef MFMA_MX

  const int gn = n0 + r31;  // column in [0,512)
  const float hv_i = hvec[gn];
  const float hv_f = hvec[gn + 512];
  const float hv_g = hvec[gn + 1024];
  const float hv_o = hvec[gn + 1536];
  const float cprev = cell[gn];
  constexpr float S = 1.f / 128.f;  // undo x8 (X) * x16 (Wih)

#define EPILOG(F, ai, af, ag, ao)                                              \
  _Pragma("unroll")                                                            \
  for (int rg = 0; rg < 4; ++rg) {                                             \
    _Pragma("unroll")                                                          \
    for (int rr = 0; rr < 4; ++rr) {                                           \
      const int reg = rg * 4 + rr;                                             \
      const int gm = m0 + wave * 64 + (F) * 32 + rr + rg * 8 + g2 * 4;         \
      float si = sigm(ai[reg] * S + hv_i);                                     \
      float sf = sigm(af[reg] * S + hv_f);                                     \
      float tg = tanh_(ag[reg] * S + hv_g);                                    \
      float so = sigm(ao[reg] * S + hv_o);                                     \
      float cnew = sf * cprev + si * tg;                                       \
      float hnew = so * tanh_(cnew);                                           \
      H[(size_t)gm * 512 + gn] = f2bf(hnew);                                   \
      if (gm == 32767) { hlast[gn] = hnew; clast[gn] = cnew; }                 \
    }                                                                          \
  }

  EPILOG(0, acc00, acc01, acc02, acc03)
  EPILOG(1, acc10, acc11, acc12, acc13)
#undef EPILOG
}

// ---------- GEMM3 v2: Q = H @ W2^T + b2 -- BARRIER-FREE streaming ----------
// Old gemm3 was the 2-phase-stall archetype: 16 kt x 2 barriers for 2 MFMAs.
// New: W2 staged to LDS once (one barrier), then a fully-unrolled 16-step
// loop with NO barriers: A-frags read DIRECT from global H (16 independent
// b128 loads -> compiler pipelines them all), B-frags from padded LDS
// (LDW=520: 2-way conflicts = free), 32 MFMAs, single coalesced Q write.
// H is a pure stream (33.5 MB read exactly once, ~5.3 us at BW floor).
__global__ __launch_bounds__(256, 2) void gemm3(
    const unsigned short* __restrict__ H,    // [32768,512] bf16
    const unsigned short* __restrict__ W2b,  // [32,512] bf16
    const float* __restrict__ b2,            // [32]
    float* __restrict__ Q) {                 // [32768,32] fp32
  constexpr int LDW = 520;
  __shared__ __align__(16) unsigned short Ws[32 * LDW];      // 32.5 KB
  const int tid = threadIdx.x, wave = tid >> 6, lane = tid & 63;
  const int id = blockIdx.x;                                 // 512 blocks
  const int m0 = ((id & 7) * 64 + (id >> 3)) * 64 + wave * 16;  // 16 rows/wave
  for (int c = tid; c < 2048; c += 256) {
    const int row = c >> 6, col8 = c & 63;
    *(uint4*)&Ws[row * LDW + col8 * 8] = *(const uint4*)(W2b + row * 512 + col8 * 8);
  }
  __syncthreads();  // only barrier in kernel

  const int fr = lane & 15, q = lane >> 4;
  f32x4 acc[2] = {};
  // A-frag (16x16x32 bf16): lane -> row fr, k = q*8 + j  (16B per lane per kt)
  const unsigned short* pH = H + (size_t)(m0 + fr) * 512 + q * 8;
#pragma unroll
  for (int kt = 0; kt < 16; ++kt) {
    const int k0 = kt * 32;
    bf16x8 a  = *(const bf16x8*)(pH + k0);
    bf16x8 b0 = *(const bf16x8*)&Ws[fr * LDW + k0 + q * 8];
    bf16x8 b1 = *(const bf16x8*)&Ws[(16 + fr) * LDW + k0 + q * 8];
    acc[0] = __builtin_amdgcn_mfma_f32_16x16x32_bf16(a, b0, acc[0], 0, 0, 0);
    acc[1] = __builtin_amdgcn_mfma_f32_16x16x32_bf16(a, b1, acc[1], 0, 0, 0);
  }

  const int rbase = q * 4;
#pragma unroll
  for (int j = 0; j < 2; ++j) {
    const int gn = j * 16 + fr;
    const float bias = b2[gn];
#pragma unroll
    for (int r = 0; r < 4; ++r) {
      const int gm = m0 + rbase + r;
      Q[(size_t)gm * 32 + gn] = acc[j][r] + bias;
    }
  }
}

// ---------- launch ----------
extern "C" void kernel_launch(void* const* d_in, const int* in_sizes, int n_in,
                              void* d_out, int out_size, void* d_ws, size_t ws_size,
                              hipStream_t stream) {
  const float* obs  = (const float*)d_in[0];
  const float* act  = (const float*)d_in[1];
  const float* hid  = (const float*)d_in[2];
  const float* cell = (const float*)d_in[3];
  const float* W1   = (const float*)d_in[4];
  const float* b1   = (const float*)d_in[5];
  const float* Wih  = (const float*)d_in[6];
  const float* bih  = (const float*)d_in[7];
  const float* Whh  = (const float*)d_in[8];
  const float* bhh  = (const float*)d_in[9];
  const float* W2   = (const float*)d_in[10];
  const float* b2   = (const float*)d_in[11];
  float* out = (float*)d_out;

  char* ws = (char*)d_ws;
  unsigned short* A0   = (unsigned short*)(ws);              // [B,544] bf16 (35,651,584 B)
  unsigned short* H    = (unsigned short*)(ws);              // alias A0 (dead after gemm1)
  unsigned char*  X8   = (unsigned char*)(ws + 35651584);    // [B,512] fp8 tiled (16,777,216 B)
  unsigned short* W1b  = (unsigned short*)(ws + 52428800);   // 557,056 B
  unsigned char*  Wih8 = (unsigned char*)(ws + 52985856);    // 1,048,576 B
  unsigned short* W2b  = (unsigned short*)(ws + 54034432);   // 32,768 B
  float*          hvec = (float*)(ws + 54067200);            // 8,192 B

  prep_all<<<4000, 256, 0, stream>>>(obs, act, W1, Wih, W2, Whh, hid, bhh, bih,
                                     A0, W1b, Wih8, W2b, hvec);
  gemm1_relu<<<1024, 256, 0, stream>>>(A0, W1b, b1, X8);
  gemm2_lstm<<<2048, 256, 0, stream>>>(X8, Wih8, hvec, cell, H,
                                       out + 32768 * 32,
                                       out + 32768 * 32 + 512);
  gemm3<<<512, 256, 0, stream>>>(H, W2b, b2, out);
}